// Round 2
// baseline (870.722 us; speedup 1.0000x reference)
//
#include <hip/hip_runtime.h>
#include <stdint.h>

// Problem constants (fixed by reference: L=1024, B=8, D=2048)
#define L_SEQ 1024
#define BATCH 8
#define DIM   2048
#define GM    8192   // L*B
#define GN    6144   // 3*D
#define GK    2048   // D
#define SCALE_X 1.7320508075688772f  // sqrt(1 + 2*exp(0))
#define SCAN_PF 16   // prefetch depth; 1024 % 16 == 0

using bf16x8  = __attribute__((ext_vector_type(8))) __bf16;
using floatx4 = __attribute__((ext_vector_type(4))) float;

__device__ __forceinline__ unsigned short f2bf(float f) {
  unsigned u = __float_as_uint(f);
  u += 0x7FFFu + ((u >> 16) & 1u);   // round-to-nearest-even
  return (unsigned short)(u >> 16);
}
__device__ __forceinline__ float bf2f(unsigned short s) {
  return __uint_as_float(((unsigned)s) << 16);
}
__device__ __forceinline__ float sigmoidf_fast(float z) {
  return __builtin_amdgcn_rcpf(1.0f + __expf(-z));
}
// async global->LDS, 16B per lane. LDS dest must be wave-uniform base + lane*16.
__device__ __forceinline__ void async16(const unsigned short* g, unsigned short* l) {
  __builtin_amdgcn_global_load_lds(
      (__attribute__((address_space(1))) unsigned int*)g,
      (__attribute__((address_space(3))) unsigned int*)l,
      16, 0, 0);
}

// ---------------- cast x (fp32) -> A (bf16), same layout (GM x GK) -------------
__global__ __launch_bounds__(256) void cast_x_kernel(const float4* __restrict__ xin,
                                                     unsigned short* __restrict__ Aout) {
  const int n4 = (GM * GK) / 4;
  for (int i = blockIdx.x * blockDim.x + threadIdx.x; i < n4; i += gridDim.x * blockDim.x) {
    float4 v = xin[i];
    union { unsigned short s[4]; unsigned long long ll; } o;
    o.s[0] = f2bf(v.x); o.s[1] = f2bf(v.y); o.s[2] = f2bf(v.z); o.s[3] = f2bf(v.w);
    *(unsigned long long*)&Aout[(size_t)i * 4] = o.ll;
  }
}

// ------------- transpose-cast W (GK x GN fp32) -> Bt (GN' x GK bf16) ------------
// Row permutation: W column n = 3d+j  ->  Bt row n' = j*DIM + d  (plane-major),
// so U's columns come out as three contiguous gate planes. GEMM is unaffected.
__global__ __launch_bounds__(256) void transpose_w_kernel(const float* __restrict__ W,
                                                          unsigned short* __restrict__ Bt) {
  __shared__ float tile[32][33];   // +1 pad: no bank conflicts
  const int tx = threadIdx.x & 31, ty = threadIdx.x >> 5;  // ty: 0..7
  const int n0 = blockIdx.x * 32;  // along GN
  const int k0 = blockIdx.y * 32;  // along GK
#pragma unroll
  for (int r = 0; r < 32; r += 8)
    tile[ty + r][tx] = W[(size_t)(k0 + ty + r) * GN + n0 + tx];
  __syncthreads();
#pragma unroll
  for (int r = 0; r < 32; r += 8) {
    const int n = n0 + ty + r;
    const int d = n / 3, j = n - 3 * d;        // magic-mul div by 3
    Bt[((size_t)j * DIM + d) * GK + k0 + tx] = f2bf(tile[tx][ty + r]);
  }
}

// ---------------- GEMM: U(GM x GN, bf16) = A(GM x GK) * Bt(GN x GK)^T -----------
// 128x128 tile / block, 4 waves in 2x2, each wave 64x64 via 4x4 MFMA 16x16x32 tiles.
__global__ __launch_bounds__(256) void gemm_kernel(const unsigned short* __restrict__ A,
                                                   const unsigned short* __restrict__ Bt,
                                                   unsigned short* __restrict__ U) {
  __shared__ alignas(16) unsigned short As[128 * 32];  // [m][k], row = 64B
  __shared__ alignas(16) unsigned short Bs[128 * 32];  // [n][k]
  const int tid  = threadIdx.x;
  const int wave = tid >> 6, lane = tid & 63;
  const int quad = lane >> 4, lrow = lane & 15;
  const int wm = (wave >> 1) * 64, wn = (wave & 1) * 64;
  const int mBase = blockIdx.y * 128, nBase = blockIdx.x * 128;

  floatx4 acc[4][4] = {};

  const int o0 = tid * 16;
  const int r0 = o0 >> 6;               // 0..63
  const int c0e = (o0 & 63) >> 1;       // bf16 col within 32
  const unsigned short* aG0 = A  + (size_t)(mBase + r0)      * GK + c0e;
  const unsigned short* aG1 = A  + (size_t)(mBase + r0 + 64) * GK + c0e;
  const unsigned short* bG0 = Bt + (size_t)(nBase + r0)      * GK + c0e;
  const unsigned short* bG1 = Bt + (size_t)(nBase + r0 + 64) * GK + c0e;
  unsigned short* asL0 = &As[o0 >> 1];
  unsigned short* asL1 = &As[(o0 >> 1) + 2048];
  unsigned short* bsL0 = &Bs[o0 >> 1];
  unsigned short* bsL1 = &Bs[(o0 >> 1) + 2048];

  for (int k0 = 0; k0 < GK; k0 += 32) {
    async16(aG0 + k0, asL0);
    async16(aG1 + k0, asL1);
    async16(bG0 + k0, bsL0);
    async16(bG1 + k0, bsL1);
    __syncthreads();

    bf16x8 aF[4], bF[4];
#pragma unroll
    for (int t = 0; t < 4; ++t) {
      aF[t] = *(const bf16x8*)&As[(wm + t * 16 + lrow) * 32 + quad * 8];
      bF[t] = *(const bf16x8*)&Bs[(wn + t * 16 + lrow) * 32 + quad * 8];
    }
#pragma unroll
    for (int mt = 0; mt < 4; ++mt)
#pragma unroll
      for (int nt = 0; nt < 4; ++nt)
        acc[mt][nt] = __builtin_amdgcn_mfma_f32_16x16x32_bf16(aF[mt], bF[nt], acc[mt][nt], 0, 0, 0);
    __syncthreads();
  }

  // C/D layout (verified m89/m91): col = lane&15 (N), row = quad*4 + reg (M)
#pragma unroll
  for (int mt = 0; mt < 4; ++mt) {
    const int gm = mBase + wm + mt * 16 + quad * 4;
#pragma unroll
    for (int nt = 0; nt < 4; ++nt) {
      const int gn = nBase + wn + nt * 16 + lrow;
#pragma unroll
      for (int r = 0; r < 4; ++r)
        U[(size_t)(gm + r) * GN + gn] = f2bf(acc[mt][nt][r]);
    }
  }
}

// ---------------- SRU scan: sequential over L, one lane per (b,d) ---------------
// U row gm = l*B + b has three gate planes: u0 at [0,D), u1 at [D,2D), u2 at [2D,3D).
// Branchless register prefetch, depth SCAN_PF; U and xbf are PADDED by SCAN_PF
// steps so the prefetch loads are unconditional (static vmcnt -> rolling waits).
__global__ __launch_bounds__(64) void sru_scan_kernel(const unsigned short* __restrict__ U,
                                                      const unsigned short* __restrict__ xbf,
                                                      const float* __restrict__ c0,
                                                      const float* __restrict__ wc,
                                                      const float* __restrict__ bias,
                                                      float* __restrict__ out) {
  const int e = blockIdx.x * 64 + threadIdx.x;  // 0..16383
  const int b = e >> 11, d = e & (DIM - 1);
  const float vf = wc[d], vr = wc[DIM + d];
  const float bfv = bias[d], brv = bias[DIM + d];
  float c = c0[e];

  constexpr int PF = SCAN_PF;
  constexpr int US = BATCH * GN;    // 49152 elements per l-step (U)
  constexpr int XS = BATCH * DIM;   // 16384 elements per l-step (x, h)

  const unsigned short* u0p = U + (size_t)b * GN + d;
  const unsigned short* xp  = xbf + (size_t)b * DIM + d;
  float* hp = out + (size_t)b * DIM + d;

  float p0[PF], p1[PF], p2[PF], px[PF];
#pragma unroll
  for (int j = 0; j < PF; ++j) {
    const unsigned short* u = u0p + (size_t)j * US;
    p0[j] = bf2f(u[0]);
    p1[j] = bf2f(u[DIM]) + bfv;
    p2[j] = bf2f(u[2 * DIM]) + brv;
    px[j] = bf2f(xp[(size_t)j * XS]) * SCALE_X;
  }
  const unsigned short* uf = u0p + (size_t)PF * US;
  const unsigned short* xf = xp + (size_t)PF * XS;

  for (int l0 = 0; l0 < L_SEQ; l0 += PF) {
#pragma unroll
    for (int j = 0; j < PF; ++j) {
      const float a0 = p0[j], A1 = p1[j], A2 = p2[j], ax = px[j];
      // unconditional prefetch (reads pad garbage on the last PF steps; discarded)
      p0[j] = bf2f(uf[0]);
      p1[j] = bf2f(uf[DIM]) + bfv;
      p2[j] = bf2f(uf[2 * DIM]) + brv;
      px[j] = bf2f(xf[0]) * SCALE_X;
      uf += US; xf += XS;
      // critical chain: fma -> sigmoid -> sub/fma  (~36 cyc/step)
      const float f = sigmoidf_fast(fmaf(vf, c, A1));
      c = fmaf(c - a0, f, a0);
      const float r = sigmoidf_fast(fmaf(vr, c, A2));
      *hp = fmaf(r, c - ax, ax);   // r*c + (1-r)*ax
      hp += XS;
    }
  }
  out[(size_t)L_SEQ * XS + e] = c;  // c_last
}

// --------------------------------- launcher ------------------------------------
extern "C" void kernel_launch(void* const* d_in, const int* in_sizes, int n_in,
                              void* d_out, int out_size, void* d_ws, size_t ws_size,
                              hipStream_t stream) {
  const float* x    = (const float*)d_in[0];  // (L,B,D)
  const float* c0   = (const float*)d_in[1];  // (B,D)
  const float* W    = (const float*)d_in[2];  // (D, 3D)
  const float* wc   = (const float*)d_in[3];  // (2D,)
  const float* bias = (const float*)d_in[4];  // (2D,)
  float* out = (float*)d_out;                 // h (L*B*D) ++ c_last (B*D)

  // Workspace layout (bytes):
  //   A_bf : GM*GK*2 = 33554432  + pad SCAN_PF*B*D*2 = 524288   -> [0, 34078720)
  //   Bt   : GN*GK*2 = 25165824                                  -> [34078720, 59244544)
  //   U_bf : GM*GN*2 = 100663296 + pad SCAN_PF*B*3D*2 = 1572864  -> [59244544, 161480704)
  char* ws = (char*)d_ws;
  unsigned short* A_bf  = (unsigned short*)(ws);
  unsigned short* Bt_bf = (unsigned short*)(ws + 34078720);
  unsigned short* U_bf  = (unsigned short*)(ws + 59244544);

  cast_x_kernel<<<4096, 256, 0, stream>>>((const float4*)x, A_bf);
  transpose_w_kernel<<<dim3(GN / 32, GK / 32), 256, 0, stream>>>(W, Bt_bf);
  gemm_kernel<<<dim3(GN / 128, GM / 128), 256, 0, stream>>>(A_bf, Bt_bf, U_bf);
  sru_scan_kernel<<<256, 64, 0, stream>>>(U_bf, A_bf, c0, wc, bias, out);
}

// Round 3
// 484.558 us; speedup vs baseline: 1.7969x; 1.7969x over previous
//
#include <hip/hip_runtime.h>
#include <stdint.h>

// Problem constants (fixed by reference: L=1024, B=8, D=2048)
#define L_SEQ 1024
#define BATCH 8
#define DIM   2048
#define GM    8192   // L*B
#define GN    6144   // 3*D
#define GK    2048   // D
#define SCALE_X 1.7320508075688772f  // sqrt(1 + 2*exp(0))
#define SCAN_PF 16   // prefetch depth; 3*PF=48 wave-loads in flight <= 63 vmcnt cap

using bf16x8  = __attribute__((ext_vector_type(8))) __bf16;
using floatx4 = __attribute__((ext_vector_type(4))) float;

__device__ __forceinline__ unsigned short f2bf(float f) {
  unsigned u = __float_as_uint(f);
  u += 0x7FFFu + ((u >> 16) & 1u);   // round-to-nearest-even
  return (unsigned short)(u >> 16);
}
__device__ __forceinline__ float sigmoidf_fast(float z) {
  return __builtin_amdgcn_rcpf(1.0f + __expf(-z));
}
// async global->LDS, 16B per lane. LDS dest must be wave-uniform base + lane*16.
__device__ __forceinline__ void async16(const unsigned short* g, unsigned short* l) {
  __builtin_amdgcn_global_load_lds(
      (__attribute__((address_space(1))) unsigned int*)g,
      (__attribute__((address_space(3))) unsigned int*)l,
      16, 0, 0);
}

// ---------------- cast x (fp32) -> A (bf16), same layout (GM x GK) -------------
__global__ __launch_bounds__(256) void cast_x_kernel(const float4* __restrict__ xin,
                                                     unsigned short* __restrict__ Aout) {
  const int n4 = (GM * GK) / 4;
  for (int i = blockIdx.x * blockDim.x + threadIdx.x; i < n4; i += gridDim.x * blockDim.x) {
    float4 v = xin[i];
    union { unsigned short s[4]; unsigned long long ll; } o;
    o.s[0] = f2bf(v.x); o.s[1] = f2bf(v.y); o.s[2] = f2bf(v.z); o.s[3] = f2bf(v.w);
    *(unsigned long long*)&Aout[(size_t)i * 4] = o.ll;
  }
}

// ------------- transpose-cast W (GK x GN fp32) -> Bt (GN' x GK bf16) ------------
// Column permutation (GEMM itself unaffected):
//   W col n = 3d+j ->  j==0: Bt row d                (u0 plane, [0,D))
//                      j==1: Bt row DIM + 2d         (u1/u2 interleaved plane)
//                      j==2: Bt row DIM + 2d + 1
// So the scan reads u0 as a ushort and (u1,u2) as ONE dword.
__global__ __launch_bounds__(256) void transpose_w_kernel(const float* __restrict__ W,
                                                          unsigned short* __restrict__ Bt) {
  __shared__ float tile[32][33];   // +1 pad: no bank conflicts
  const int tx = threadIdx.x & 31, ty = threadIdx.x >> 5;  // ty: 0..7
  const int n0 = blockIdx.x * 32;  // along GN
  const int k0 = blockIdx.y * 32;  // along GK
#pragma unroll
  for (int r = 0; r < 32; r += 8)
    tile[ty + r][tx] = W[(size_t)(k0 + ty + r) * GN + n0 + tx];
  __syncthreads();
#pragma unroll
  for (int r = 0; r < 32; r += 8) {
    const int n = n0 + ty + r;
    const int dq = n / 3, j = n - 3 * dq;      // magic-mul div by 3
    const int np = (j == 0) ? dq : (DIM + 2 * dq + (j - 1));
    Bt[(size_t)np * GK + k0 + tx] = f2bf(tile[tx][ty + r]);
  }
}

// ---------------- GEMM: U(GM x GN, bf16) = A(GM x GK) * Bt(GN x GK)^T -----------
// 128x128 tile / block, 4 waves in 2x2, each wave 64x64 via 4x4 MFMA 16x16x32 tiles.
__global__ __launch_bounds__(256) void gemm_kernel(const unsigned short* __restrict__ A,
                                                   const unsigned short* __restrict__ Bt,
                                                   unsigned short* __restrict__ U) {
  __shared__ alignas(16) unsigned short As[128 * 32];  // [m][k], row = 64B
  __shared__ alignas(16) unsigned short Bs[128 * 32];  // [n][k]
  const int tid  = threadIdx.x;
  const int wave = tid >> 6, lane = tid & 63;
  const int quad = lane >> 4, lrow = lane & 15;
  const int wm = (wave >> 1) * 64, wn = (wave & 1) * 64;
  const int mBase = blockIdx.y * 128, nBase = blockIdx.x * 128;

  floatx4 acc[4][4] = {};

  const int o0 = tid * 16;
  const int r0 = o0 >> 6;               // 0..63
  const int c0e = (o0 & 63) >> 1;       // bf16 col within 32
  const unsigned short* aG0 = A  + (size_t)(mBase + r0)      * GK + c0e;
  const unsigned short* aG1 = A  + (size_t)(mBase + r0 + 64) * GK + c0e;
  const unsigned short* bG0 = Bt + (size_t)(nBase + r0)      * GK + c0e;
  const unsigned short* bG1 = Bt + (size_t)(nBase + r0 + 64) * GK + c0e;
  unsigned short* asL0 = &As[o0 >> 1];
  unsigned short* asL1 = &As[(o0 >> 1) + 2048];
  unsigned short* bsL0 = &Bs[o0 >> 1];
  unsigned short* bsL1 = &Bs[(o0 >> 1) + 2048];

  for (int k0 = 0; k0 < GK; k0 += 32) {
    async16(aG0 + k0, asL0);
    async16(aG1 + k0, asL1);
    async16(bG0 + k0, bsL0);
    async16(bG1 + k0, bsL1);
    __syncthreads();

    bf16x8 aF[4], bF[4];
#pragma unroll
    for (int t = 0; t < 4; ++t) {
      aF[t] = *(const bf16x8*)&As[(wm + t * 16 + lrow) * 32 + quad * 8];
      bF[t] = *(const bf16x8*)&Bs[(wn + t * 16 + lrow) * 32 + quad * 8];
    }
#pragma unroll
    for (int mt = 0; mt < 4; ++mt)
#pragma unroll
      for (int nt = 0; nt < 4; ++nt)
        acc[mt][nt] = __builtin_amdgcn_mfma_f32_16x16x32_bf16(aF[mt], bF[nt], acc[mt][nt], 0, 0, 0);
    __syncthreads();
  }

  // C/D layout (verified m89/m91): col = lane&15 (N), row = quad*4 + reg (M)
#pragma unroll
  for (int mt = 0; mt < 4; ++mt) {
    const int gm = mBase + wm + mt * 16 + quad * 4;
#pragma unroll
    for (int nt = 0; nt < 4; ++nt) {
      const int gn = nBase + wn + nt * 16 + lrow;
#pragma unroll
      for (int r = 0; r < 4; ++r)
        U[(size_t)(gm + r) * GN + gn] = f2bf(acc[mt][nt][r]);
    }
  }
}

// ---------------- SRU scan: sequential over L, one lane per (b,d) ---------------
// U row gm = l*B + b: u0 plane at [0,D), interleaved (u1,u2) pairs at [D,3D).
// Rotating register prefetch, depth SCAN_PF. CRITICAL: prefetched values are kept
// as RAW uints (no ALU touch) until consumed PF iterations later, so the compiler
// can emit rolling s_waitcnt vmcnt(N) instead of draining per step.
// U and xbf regions are padded by SCAN_PF steps; tail prefetches read pad garbage
// that is never consumed.
__global__ __launch_bounds__(64) void sru_scan_kernel(const unsigned short* __restrict__ U,
                                                      const unsigned short* __restrict__ xbf,
                                                      const float* __restrict__ c0,
                                                      const float* __restrict__ wc,
                                                      const float* __restrict__ bias,
                                                      float* __restrict__ out) {
  const int e = blockIdx.x * 64 + threadIdx.x;  // 0..16383
  const int b = e >> 11, d = e & (DIM - 1);
  const float vf = wc[d], vr = wc[DIM + d];
  const float bfv = bias[d], brv = bias[DIM + d];
  float c = c0[e];

  constexpr int PF = SCAN_PF;
  constexpr int US = BATCH * GN;    // U elements per l-step
  constexpr int XS = BATCH * DIM;   // x/h elements per l-step

  const unsigned short* u0p  = U + (size_t)b * GN + d;
  const unsigned short* u12p = U + (size_t)b * GN + DIM + 2 * d;  // dword-aligned
  const unsigned short* xp   = xbf + (size_t)b * DIM + d;
  float* hp = out + (size_t)b * DIM + d;

  unsigned pu0[PF], pu12[PF], pux[PF];
#pragma unroll
  for (int j = 0; j < PF; ++j) {
    pu0[j]  = u0p[(size_t)j * US];
    pu12[j] = *(const unsigned*)(u12p + (size_t)j * US);
    pux[j]  = xp[(size_t)j * XS];
  }
  const unsigned short* uf0  = u0p + (size_t)PF * US;
  const unsigned short* uf12 = u12p + (size_t)PF * US;
  const unsigned short* xf   = xp + (size_t)PF * XS;

  for (int l0 = 0; l0 < L_SEQ; l0 += PF) {
#pragma unroll
    for (int j = 0; j < PF; ++j) {
      const unsigned r0 = pu0[j], r12 = pu12[j], rx = pux[j];
      // unconditional raw prefetch: load -> register, untouched for PF steps
      pu0[j]  = uf0[0];
      pu12[j] = *(const unsigned*)uf12;
      pux[j]  = xf[0];
      uf0 += US; uf12 += US; xf += XS;
      // decode previous-generation values (1 VALU op each)
      const float a0 = __uint_as_float(r0 << 16);
      const float u1 = __uint_as_float(r12 << 16);
      const float u2 = __uint_as_float(r12 & 0xFFFF0000u);
      const float ax = __uint_as_float(rx << 16) * SCALE_X;
      // recurrence
      const float f = sigmoidf_fast(u1 + fmaf(vf, c, bfv));
      c = fmaf(c - a0, f, a0);
      const float r = sigmoidf_fast(u2 + fmaf(vr, c, brv));
      *hp = fmaf(r, c - ax, ax);   // r*c + (1-r)*ax
      hp += XS;
    }
  }
  out[(size_t)L_SEQ * XS + e] = c;  // c_last
}

// --------------------------------- launcher ------------------------------------
extern "C" void kernel_launch(void* const* d_in, const int* in_sizes, int n_in,
                              void* d_out, int out_size, void* d_ws, size_t ws_size,
                              hipStream_t stream) {
  const float* x    = (const float*)d_in[0];  // (L,B,D)
  const float* c0   = (const float*)d_in[1];  // (B,D)
  const float* W    = (const float*)d_in[2];  // (D, 3D)
  const float* wc   = (const float*)d_in[3];  // (2D,)
  const float* bias = (const float*)d_in[4];  // (2D,)
  float* out = (float*)d_out;                 // h (L*B*D) ++ c_last (B*D)

  // Workspace layout (bytes):
  //   A_bf : GM*GK*2 = 33554432  + pad SCAN_PF*B*D*2 = 524288   -> [0, 34078720)
  //   Bt   : GN*GK*2 = 25165824                                  -> [34078720, 59244544)
  //   U_bf : GM*GN*2 = 100663296 + pad SCAN_PF*B*3D*2 = 1572864  -> [59244544, 161480704)
  char* ws = (char*)d_ws;
  unsigned short* A_bf  = (unsigned short*)(ws);
  unsigned short* Bt_bf = (unsigned short*)(ws + 34078720);
  unsigned short* U_bf  = (unsigned short*)(ws + 59244544);

  cast_x_kernel<<<4096, 256, 0, stream>>>((const float4*)x, A_bf);
  transpose_w_kernel<<<dim3(GN / 32, GK / 32), 256, 0, stream>>>(W, Bt_bf);
  gemm_kernel<<<dim3(GN / 128, GM / 128), 256, 0, stream>>>(A_bf, Bt_bf, U_bf);
  sru_scan_kernel<<<256, 64, 0, stream>>>(U_bf, A_bf, c0, wc, bias, out);
}

// Round 4
// 478.019 us; speedup vs baseline: 1.8215x; 1.0137x over previous
//
#include <hip/hip_runtime.h>
#include <stdint.h>

// Problem constants (fixed by reference: L=1024, B=8, D=2048)
#define L_SEQ 1024
#define BATCH 8
#define DIM   2048
#define GM    8192   // L*B
#define GN    6144   // 3*D
#define GK    2048   // D
#define SCALE_X 1.7320508075688772f  // sqrt(1 + 2*exp(0))
#define SCAN_PF 16
#define W_ILV  8192  // U' row width (elements) when x is interleaved

using bf16x8  = __attribute__((ext_vector_type(8))) __bf16;
using floatx4 = __attribute__((ext_vector_type(4))) float;

__device__ __forceinline__ unsigned short f2bf(float f) {
  unsigned u = __float_as_uint(f);
  u += 0x7FFFu + ((u >> 16) & 1u);   // round-to-nearest-even
  return (unsigned short)(u >> 16);
}
__device__ __forceinline__ float sigmoidf_fast(float z) {
  return __builtin_amdgcn_rcpf(1.0f + __expf(-z));
}
__device__ __forceinline__ void async16(const unsigned short* g, unsigned short* l) {
  __builtin_amdgcn_global_load_lds(
      (__attribute__((address_space(1))) unsigned int*)g,
      (__attribute__((address_space(3))) unsigned int*)l,
      16, 0, 0);
}

// ---------------- cast x (fp32) -> A (bf16); ILV also scatters x into U' -------
template <bool ILV>
__global__ __launch_bounds__(256) void cast_x_kernel(const float4* __restrict__ xin,
                                                     unsigned short* __restrict__ Aout,
                                                     unsigned short* __restrict__ Ux) {
  const int n4 = (GM * GK) / 4;
  for (int i = blockIdx.x * blockDim.x + threadIdx.x; i < n4; i += gridDim.x * blockDim.x) {
    float4 v = xin[i];
    union { unsigned short s[4]; unsigned long long ll; } o;
    o.s[0] = f2bf(v.x); o.s[1] = f2bf(v.y); o.s[2] = f2bf(v.z); o.s[3] = f2bf(v.w);
    *(unsigned long long*)&Aout[(size_t)i * 4] = o.ll;
    if (ILV) {
      const int f = i * 4;                    // flat (gm,d); d..d+3 in one row
      const int gm = f >> 11, d = f & (DIM - 1);
      unsigned short* dst = Ux + (size_t)gm * W_ILV + 2 * d + 1;  // odd slots
      dst[0] = o.s[0]; dst[2] = o.s[1]; dst[4] = o.s[2]; dst[6] = o.s[3];
    }
  }
}

// ------------- transpose-cast W (GK x GN fp32) -> Bt (GN' x GK bf16) ------------
// Column permutation: W col n = 3d+j -> j==0: Bt row d (u0 plane)
//                                       j>0 : Bt row DIM + 2d + (j-1) (u1u2 pairs)
__global__ __launch_bounds__(256) void transpose_w_kernel(const float* __restrict__ W,
                                                          unsigned short* __restrict__ Bt) {
  __shared__ float tile[32][33];
  const int tx = threadIdx.x & 31, ty = threadIdx.x >> 5;
  const int n0 = blockIdx.x * 32;
  const int k0 = blockIdx.y * 32;
#pragma unroll
  for (int r = 0; r < 32; r += 8)
    tile[ty + r][tx] = W[(size_t)(k0 + ty + r) * GN + n0 + tx];
  __syncthreads();
#pragma unroll
  for (int r = 0; r < 32; r += 8) {
    const int n = n0 + ty + r;
    const int dq = n / 3, j = n - 3 * dq;
    const int np = (j == 0) ? dq : (DIM + 2 * dq + (j - 1));
    Bt[(size_t)np * GK + k0 + tx] = f2bf(tile[tx][ty + r]);
  }
}

// ---------------- GEMM: U = A(GM x GK) * Bt(GN x GK)^T, bf16 out ----------------
// 128x128 block tile, BK=64 (32 KB LDS, 32 barrier-pairs), 4 waves 2x2, each wave
// 64x64 via 4x4 MFMA 16x16x32. LDS rows are 128 B with XOR chunk swizzle
// s = c ^ (row&7): ds_read_b128 bank group = 4*s -> injective over any 8
// consecutive lanes -> conflict-free. Swizzle applied by permuting each lane's
// GLOBAL source chunk at staging (LDS side of global_load_lds stays lane-linear).
template <bool ILV>
__global__ __launch_bounds__(256) void gemm_kernel(const unsigned short* __restrict__ A,
                                                   const unsigned short* __restrict__ Bt,
                                                   unsigned short* __restrict__ U) {
  __shared__ alignas(16) unsigned short As[128 * 64];  // 16 KB, [row][64k]
  __shared__ alignas(16) unsigned short Bs[128 * 64];
  const int tid  = threadIdx.x;
  const int wave = tid >> 6, lane = tid & 63;
  const int quad = lane >> 4, lrow = lane & 15;
  const int wm = (wave >> 1) * 64, wn = (wave & 1) * 64;
  const int mBase = blockIdx.y * 128, nBase = blockIdx.x * 128;

  floatx4 acc[4][4] = {};

  // staging decomposition: lane -> (row r, lds slot sC); global chunk cg = sC ^ (r&7)
  const int r  = tid >> 3;                 // 0..31 (rows per issue = 32)
  const int sC = tid & 7;
  const int cg = sC ^ (r & 7);
  const unsigned short* aG0 = A  + (size_t)(mBase + r) * GK + cg * 8;
  const unsigned short* bG0 = Bt + (size_t)(nBase + r) * GK + cg * 8;
  unsigned short* asD = &As[tid * 8];
  unsigned short* bsD = &Bs[tid * 8];
  const int swz = lrow & 7;

  for (int k0 = 0; k0 < GK; k0 += 64) {
#pragma unroll
    for (int i = 0; i < 4; ++i) async16(aG0 + (size_t)i * 32 * GK + k0, asD + i * 2048);
#pragma unroll
    for (int i = 0; i < 4; ++i) async16(bG0 + (size_t)i * 32 * GK + k0, bsD + i * 2048);
    __syncthreads();

#pragma unroll
    for (int kk = 0; kk < 2; ++kk) {
      const int s = (kk * 4 + quad) ^ swz;   // swizzled 16B slot
      bf16x8 aF[4], bF[4];
#pragma unroll
      for (int t = 0; t < 4; ++t) {
        aF[t] = *(const bf16x8*)&As[(wm + t * 16 + lrow) * 64 + s * 8];
        bF[t] = *(const bf16x8*)&Bs[(wn + t * 16 + lrow) * 64 + s * 8];
      }
#pragma unroll
      for (int mt = 0; mt < 4; ++mt)
#pragma unroll
        for (int nt = 0; nt < 4; ++nt)
          acc[mt][nt] = __builtin_amdgcn_mfma_f32_16x16x32_bf16(aF[mt], bF[nt], acc[mt][nt], 0, 0, 0);
    }
    __syncthreads();
  }

  // C/D layout: col = lane&15 (N), row = quad*4 + reg (M)
  const int rowW = ILV ? W_ILV : GN;
#pragma unroll
  for (int mt = 0; mt < 4; ++mt) {
    const int gm = mBase + wm + mt * 16 + quad * 4;
#pragma unroll
    for (int nt = 0; nt < 4; ++nt) {
      const int gn = nBase + wn + nt * 16 + lrow;
      const int col = ILV ? ((gn < DIM) ? 2 * gn : gn + DIM) : gn;  // u0 even slots / u1u2 block
#pragma unroll
      for (int q = 0; q < 4; ++q)
        U[(size_t)(gm + q) * rowW + col] = f2bf(acc[mt][nt][q]);
    }
  }
}

// ---------------- SRU scan (ILV): 2 dword loads + 1 store per step --------------
// U' row gm: [ (u0,x) pairs, 2D elems ][ (u1,u2) pairs, 2D elems ].
// Rotating raw-register prefetch depth 16 -> 48 outstanding vm-ops (<=63 cap).
__global__ __launch_bounds__(64) void sru_scan_ilv(const unsigned short* __restrict__ U,
                                                   const float* __restrict__ c0,
                                                   const float* __restrict__ wc,
                                                   const float* __restrict__ bias,
                                                   float* __restrict__ out) {
  const int e = blockIdx.x * 64 + threadIdx.x;
  const int b = e >> 11, d = e & (DIM - 1);
  const float vf = wc[d], vr = wc[DIM + d];
  const float bfv = bias[d], brv = bias[DIM + d];
  float c = c0[e];

  constexpr int PF = SCAN_PF;
  constexpr int UD = BATCH * W_ILV / 2;  // dwords per l-step in U'
  constexpr int XS = BATCH * DIM;

  const unsigned* u0x = (const unsigned*)(U + (size_t)b * W_ILV + 2 * d);
  const unsigned* u12 = (const unsigned*)(U + (size_t)b * W_ILV + 2 * DIM + 2 * d);
  float* hp = out + (size_t)b * DIM + d;

  unsigned p0x[PF], p12[PF];
#pragma unroll
  for (int j = 0; j < PF; ++j) {
    p0x[j] = u0x[(size_t)j * UD];
    p12[j] = u12[(size_t)j * UD];
  }
  const unsigned* f0x = u0x + (size_t)PF * UD;
  const unsigned* f12 = u12 + (size_t)PF * UD;

  for (int l0 = 0; l0 < L_SEQ; l0 += PF) {
#pragma unroll
    for (int j = 0; j < PF; ++j) {
      const unsigned ra = p0x[j], rb = p12[j];
      p0x[j] = *f0x; p12[j] = *f12;        // raw prefetch, consumed PF iters later
      f0x += UD; f12 += UD;
      const float a0 = __uint_as_float(ra << 16);
      const float ax = __uint_as_float(ra & 0xFFFF0000u) * SCALE_X;
      const float u1 = __uint_as_float(rb << 16);
      const float u2 = __uint_as_float(rb & 0xFFFF0000u);
      const float f = sigmoidf_fast(u1 + fmaf(vf, c, bfv));
      c = fmaf(c - a0, f, a0);
      const float rr = sigmoidf_fast(u2 + fmaf(vr, c, brv));
      *hp = fmaf(rr, c - ax, ax);
      hp += XS;
    }
  }
  out[(size_t)L_SEQ * XS + e] = c;
}

// ---------------- SRU scan (fallback, r3 layout: separate x in A_bf) ------------
__global__ __launch_bounds__(64) void sru_scan_flat(const unsigned short* __restrict__ U,
                                                    const unsigned short* __restrict__ xbf,
                                                    const float* __restrict__ c0,
                                                    const float* __restrict__ wc,
                                                    const float* __restrict__ bias,
                                                    float* __restrict__ out) {
  const int e = blockIdx.x * 64 + threadIdx.x;
  const int b = e >> 11, d = e & (DIM - 1);
  const float vf = wc[d], vr = wc[DIM + d];
  const float bfv = bias[d], brv = bias[DIM + d];
  float c = c0[e];

  constexpr int PF = SCAN_PF;
  constexpr int US = BATCH * GN;
  constexpr int XS = BATCH * DIM;

  const unsigned short* u0p  = U + (size_t)b * GN + d;
  const unsigned short* u12p = U + (size_t)b * GN + DIM + 2 * d;
  const unsigned short* xp   = xbf + (size_t)b * DIM + d;
  float* hp = out + (size_t)b * DIM + d;

  unsigned pu0[PF], pu12[PF], pux[PF];
#pragma unroll
  for (int j = 0; j < PF; ++j) {
    pu0[j]  = u0p[(size_t)j * US];
    pu12[j] = *(const unsigned*)(u12p + (size_t)j * US);
    pux[j]  = xp[(size_t)j * XS];
  }
  const unsigned short* uf0  = u0p + (size_t)PF * US;
  const unsigned short* uf12 = u12p + (size_t)PF * US;
  const unsigned short* xf   = xp + (size_t)PF * XS;

  for (int l0 = 0; l0 < L_SEQ; l0 += PF) {
#pragma unroll
    for (int j = 0; j < PF; ++j) {
      const unsigned r0 = pu0[j], r12 = pu12[j], rx = pux[j];
      pu0[j]  = uf0[0];
      pu12[j] = *(const unsigned*)uf12;
      pux[j]  = xf[0];
      uf0 += US; uf12 += US; xf += XS;
      const float a0 = __uint_as_float(r0 << 16);
      const float u1 = __uint_as_float(r12 << 16);
      const float u2 = __uint_as_float(r12 & 0xFFFF0000u);
      const float ax = __uint_as_float(rx << 16) * SCALE_X;
      const float f = sigmoidf_fast(u1 + fmaf(vf, c, bfv));
      c = fmaf(c - a0, f, a0);
      const float rr = sigmoidf_fast(u2 + fmaf(vr, c, brv));
      *hp = fmaf(rr, c - ax, ax);
      hp += XS;
    }
  }
  out[(size_t)L_SEQ * XS + e] = c;
}

// --------------------------------- launcher ------------------------------------
extern "C" void kernel_launch(void* const* d_in, const int* in_sizes, int n_in,
                              void* d_out, int out_size, void* d_ws, size_t ws_size,
                              hipStream_t stream) {
  const float* x    = (const float*)d_in[0];
  const float* c0   = (const float*)d_in[1];
  const float* W    = (const float*)d_in[2];
  const float* wc   = (const float*)d_in[3];
  const float* bias = (const float*)d_in[4];
  float* out = (float*)d_out;

  char* ws = (char*)d_ws;
  // ILV layout: A 33,554,432 | Bt 25,165,824 | U' 134,217,728 + pad 2,097,152
  const size_t ILV_NEED = 33554432u + 25165824u + 134217728u + 2097152u;  // 195,035,136

  if (ws_size >= ILV_NEED) {
    unsigned short* A_bf  = (unsigned short*)(ws);
    unsigned short* Bt_bf = (unsigned short*)(ws + 33554432);
    unsigned short* U_bf  = (unsigned short*)(ws + 58720256);
    cast_x_kernel<true><<<4096, 256, 0, stream>>>((const float4*)x, A_bf, U_bf);
    transpose_w_kernel<<<dim3(GN / 32, GK / 32), 256, 0, stream>>>(W, Bt_bf);
    gemm_kernel<true><<<dim3(GN / 128, GM / 128), 256, 0, stream>>>(A_bf, Bt_bf, U_bf);
    sru_scan_ilv<<<256, 64, 0, stream>>>(U_bf, c0, wc, bias, out);
  } else {
    // r3 layout: A (+scan pad) | Bt | U (GN width, + pad)
    unsigned short* A_bf  = (unsigned short*)(ws);
    unsigned short* Bt_bf = (unsigned short*)(ws + 34078720);
    unsigned short* U_bf  = (unsigned short*)(ws + 59244544);
    cast_x_kernel<false><<<4096, 256, 0, stream>>>((const float4*)x, A_bf, nullptr);
    transpose_w_kernel<<<dim3(GN / 32, GK / 32), 256, 0, stream>>>(W, Bt_bf);
    gemm_kernel<false><<<dim3(GN / 128, GM / 128), 256, 0, stream>>>(A_bf, Bt_bf, U_bf);
    sru_scan_flat<<<256, 64, 0, stream>>>(U_bf, A_bf, c0, wc, bias, out);
  }
}